// Round 7
// baseline (752.250 us; speedup 1.0000x reference)
//
#include <hip/hip_runtime.h>
#include <math.h>

#define NCLS 81
#define NANCH 8732
#define NB 64
#define BUCKET_STRIDE 16     // 64 B cacheline spread for int buckets
#define HSTRIDE 257          // bank-decorrelated histogram copy stride (ints)
#define NLOC_BLK  2240       // 35 chunks * 64 batch rows (first in grid)
#define NCONF_BLK 1792       // persistent conf blocks
#define NSEL_BLK  64         // trailing selector blocks (one per batch row)
#define NTILES 17464         // 558848 anchors / 32 per tile
#define TILE_A 32            // anchors per tile (8 per wave)
#define WAVE_F 648           // floats per wave per tile (8 anchors * 81)
#define DONE_TARGET (NLOC_BLK + NCONF_BLK)

#define ALD_I(p) __hip_atomic_load((p), __ATOMIC_RELAXED, __HIP_MEMORY_SCOPE_AGENT)
#define ALD_F(p) __hip_atomic_load((p), __ATOMIC_RELAXED, __HIP_MEMORY_SCOPE_AGENT)

struct ConfSh {
    float sx[2][2592];       // double-buffered pred tiles (4 waves * 648)
    int labels[2][32];
    float red[4];
};
struct SelSh {
    float cl[NANCH];         // 34928 B
    int hist[4 * HSTRIDE];   // 4112 B
    int wsum[4];
    float fred[4];
    int numpos;
    unsigned int prefix;
    int k;
    int thr;
};
union ShMem { ConfSh c; SelSh s; };   // ~39.1 KB -> 4 blocks/CU

// --------- ONE fused kernel: loc partials + persistent pipelined conf + select ---------
// Block roles by blockIdx: [0,NLOC): loc partial sums; [NLOC,NLOC+NCONF): conf
// (2-deep DMA pipeline, wave-private LDS, zero barriers in the loop);
// [NLOC+NCONF, +64): selectors. Selectors spin on a device-scope done counter
// (safe under ANY dispatch order: <=64 spinners << resident capacity, so
// producers always have slots). All cross-block data reads in the selector use
// agent-scope atomic loads (per-XCD L2s are not coherent for plain loads within
// a single kernel); producers __threadfence() before their done-increment.
__global__ __launch_bounds__(256) void fused_kernel(
    const float* __restrict__ pred_conf,
    const float* __restrict__ gt_conf,
    const float* __restrict__ pred_loc,
    const float* __restrict__ gt_loc,
    float* __restrict__ cl_out,       // [B*N] cl_neg (0 for positives)
    int* __restrict__ pos_buckets,    // [64*BUCKET_STRIDE], pre-zeroed
    float* __restrict__ row_pos,      // [128] per-row positive-loss sums, pre-zeroed
    float* __restrict__ locp,         // [2240] loc per-block partials
    int* __restrict__ done,           // completion counter, pre-zeroed
    float* __restrict__ out)          // [128] final outputs (written by selectors)
{
    __shared__ ShMem sh;

    const int tid = threadIdx.x;
    const int lane = tid & 63, w = tid >> 6;

    if (blockIdx.x < NLOC_BLK) {
        // ---- loc: smooth-L1-quirk loss; one partial per block ----
        const int bid = blockIdx.x;
        const int b = bid & 63;
        const int chunk = bid >> 6;     // 0..34
        const int idx = chunk * 256 + tid;
        float local = 0.f;
        if (idx < NANCH) {
            const float4* p = (const float4*)(pred_loc + (size_t)b * (NANCH * 4));
            const float4* g = (const float4*)(gt_loc + (size_t)b * (NANCH * 4));
            float4 pv = p[idx];
            float4 gv = g[idx];
            float a0 = fabsf(pv.x - gv.x), a1 = fabsf(pv.y - gv.y);
            float a2 = fabsf(pv.z - gv.z), a3 = fabsf(pv.w - gv.w);
            local  = (a0 > 1.f) ? (a0 - 0.5f) : 0.f;
            local += (a1 > 1.f) ? (a1 - 0.5f) : 0.f;
            local += (a2 > 1.f) ? (a2 - 0.5f) : 0.f;
            local += (a3 > 1.f) ? (a3 - 0.5f) : 0.f;
        }
        for (int off = 32; off; off >>= 1) local += __shfl_xor(local, off);
        if (lane == 0) sh.c.red[w] = local;
        __syncthreads();
        if (tid == 0) {
            locp[bid] = sh.c.red[0] + sh.c.red[1] + sh.c.red[2] + sh.c.red[3];
            __threadfence();
            atomicAdd(done, 1);
        }
        return;
    }

    if (blockIdx.x < NLOC_BLK + NCONF_BLK) {
        // ---- conf: persistent, 2-deep pipelined, wave-private ----
        const int pid = blockIdx.x - NLOC_BLK;        // 0..1791
        float* swA = &sh.c.sx[0][w * WAVE_F];
        float* swB = &sh.c.sx[1][w * WAVE_F];
        int pacc = 0;

#define DMA3(dst, src)                                                              \
    do {                                                                            \
        __builtin_amdgcn_global_load_lds(                                           \
            (const __attribute__((address_space(1))) unsigned int*)((src) + lane),  \
            (__attribute__((address_space(3))) unsigned int*)(&(dst)[lane * 4]),    \
            16, 0, 0);                                                              \
        __builtin_amdgcn_global_load_lds(                                           \
            (const __attribute__((address_space(1))) unsigned int*)((src) + 64 + lane), \
            (__attribute__((address_space(3))) unsigned int*)(&(dst)[(64 + lane) * 4]), \
            16, 0, 0);                                                              \
        if (lane < 34)                                                              \
            __builtin_amdgcn_global_load_lds(                                       \
                (const __attribute__((address_space(1))) unsigned int*)((src) + 128 + lane), \
                (__attribute__((address_space(3))) unsigned int*)(&(dst)[(128 + lane) * 4]), \
                16, 0, 0);                                                          \
    } while (0)

        int T = pid;
        {
            const float4* ps = (const float4*)(pred_conf + (size_t)T * 2592 + w * WAVE_F);
            DMA3(swA, ps);
        }
        const float4* gs = (const float4*)(gt_conf + (size_t)T * 2592 + w * WAVE_F);
        float4 g0 = gs[lane];
        float4 g1 = gs[64 + lane];
        float4 g2 = (lane < 34) ? gs[128 + lane] : float4{0.f, 0.f, 0.f, 0.f};

        int cur = 0;
        for (;;) {
            const int Tn = T + NCONF_BLK;
            const bool hasN = (Tn < NTILES);
            float* swc = cur ? swB : swA;
            float* swn = cur ? swA : swB;

            if (hasN) {
                const float4* ps = (const float4*)(pred_conf + (size_t)Tn * 2592 + w * WAVE_F);
                DMA3(swn, ps);
                asm volatile("s_waitcnt vmcnt(3)" ::: "memory");   // retire tile T's DMA+gt
            } else {
                asm volatile("s_waitcnt vmcnt(0)" ::: "memory");
            }
            __builtin_amdgcn_sched_barrier(0);

            {   // gt regs (tile T) -> wave-private labels
                const float4 gg[3] = {g0, g1, g2};
#pragma unroll
                for (int c = 0; c < 3; ++c) {
                    const int f4 = c * 64 + lane;
                    float gv[4] = {gg[c].x, gg[c].y, gg[c].z, gg[c].w};
#pragma unroll
                    for (int t = 0; t < 4; ++t) {
                        if (gv[t] != 0.0f) {
                            const int e = 4 * f4 + t;            // < 648
                            const int a = e / 81, cls = e - 81 * a;
                            sh.c.labels[cur][w * 8 + a] = cls;
                            pacc += (cls != 0);
                        }
                    }
                }
            }
            if (hasN) {
                const float4* gn = (const float4*)(gt_conf + (size_t)Tn * 2592 + w * WAVE_F);
                g0 = gn[lane];
                g1 = gn[64 + lane];
                g2 = (lane < 34) ? gn[128 + lane] : float4{0.f, 0.f, 0.f, 0.f};
            }
            asm volatile("s_waitcnt lgkmcnt(0)" ::: "memory");
            __builtin_amdgcn_sched_barrier(0);

            {   // consume tile T: 8 lanes per anchor
                const int a = lane >> 3, r = lane & 7;
                const float* xr = swc + a * 81;
                float s = 0.f;
#pragma unroll
                for (int j = 0; j < 10; ++j) s += __expf(xr[r + 8 * j]);
                if (r == 0) s += __expf(xr[80]);
                s += __shfl_xor(s, 1);
                s += __shfl_xor(s, 2);
                s += __shfl_xor(s, 4);
                const float lse = __logf(s);

                const int anchor = T * TILE_A + w * 8 + a;
                float contrib = 0.f;
                if (r == 0) {
                    const int lbl = sh.c.labels[cur][w * 8 + a];
                    const float cl = lse - xr[lbl];
                    const bool posf = (lbl != 0);
                    cl_out[anchor] = posf ? 0.0f : cl;
                    if (posf) contrib = cl;
                }
                const int b = anchor / NANCH;
                const int bF = __builtin_amdgcn_readfirstlane(b);
                float c0 = (b == bF) ? contrib : 0.0f;
                float c1 = contrib - c0;
                for (int off = 32; off; off >>= 1) {
                    c0 += __shfl_xor(c0, off);
                    c1 += __shfl_xor(c1, off);
                }
                if (lane == 0) {
                    if (c0 != 0.f) atomicAdd(&row_pos[bF], c0);
                    if (c1 != 0.f) atomicAdd(&row_pos[bF + 1], c1);
                }
            }

            if (!hasN) break;
            T = Tn;
            cur ^= 1;
        }
#undef DMA3

        for (int off = 32; off; off >>= 1) pacc += __shfl_xor(pacc, off);
        if (lane == 0 && pacc)
            atomicAdd(&pos_buckets[(((pid << 2) | w) & 63) * BUCKET_STRIDE], pacc);

        __threadfence();          // every thread flushes its cl_out stores
        __syncthreads();
        if (tid == 0) atomicAdd(done, 1);
        return;
    }

    // ---- selector: one block per batch row; radix-256 select (256 threads) ----
    const int b = blockIdx.x - (NLOC_BLK + NCONF_BLK);

    if (tid == 0) {
        while (ALD_I(done) < DONE_TARGET) __builtin_amdgcn_s_sleep(8);
    }
    __syncthreads();
    __threadfence();

    if (tid < 64) {
        int v = ALD_I(&pos_buckets[tid * BUCKET_STRIDE]);
        for (int off = 32; off; off >>= 1) v += __shfl_xor(v, off);
        if (tid == 0) sh.s.numpos = v;
    } else if (tid < 128) {
        float v = (lane < 35) ? ALD_F(&locp[lane * 64 + b]) : 0.f;
        for (int off = 32; off; off >>= 1) v += __shfl_xor(v, off);
        if (lane == 0) out[64 + b] = v;
    }

    // fill cl[] via batched coherent loads (8-deep MLP), strided/coalesced
    float* rowp = (float*)(cl_out + (size_t)b * NANCH);
    float* cl = sh.s.cl;
    for (int it0 = 0; it0 < 32; it0 += 8) {
        float t[8];
#pragma unroll
        for (int j = 0; j < 8; ++j) t[j] = ALD_F(rowp + tid + 256 * (it0 + j));  // max 8191 < NANCH
#pragma unroll
        for (int j = 0; j < 8; ++j) cl[tid + 256 * (it0 + j)] = t[j];
    }
    {
        float t[3];
#pragma unroll
        for (int j = 0; j < 3; ++j) {
            const int i = tid + 256 * (32 + j);
            t[j] = (i < NANCH) ? ALD_F(rowp + i) : 0.f;
        }
#pragma unroll
        for (int j = 0; j < 3; ++j) {
            const int i = tid + 256 * (32 + j);
            if (i < NANCH) cl[i] = t[j];
        }
    }
    __syncthreads();

    int k = 3 * sh.s.numpos;             // ref: int(3.0 * num_pos), global scalar
    if (k > NANCH - 1) k = NANCH - 1;
    if (k < 0) k = 0;

    const int hofs = w * HSTRIDE;
    unsigned int prefix = 0u;
    for (int r = 0; r < 4; ++r) {
        const int shift = 24 - 8 * r;
        const unsigned int maskHigh = (r == 0) ? 0u : (0xFFFFFFFFu << (shift + 8));
        for (int j = tid; j < 4 * HSTRIDE; j += 256) sh.s.hist[j] = 0;
        __syncthreads();
        if (r == 0) {
            // wave-aggregated histogram of the exponent byte
            for (int i0 = 0; i0 < 8960; i0 += 256) {
                int i = i0 + tid;
                bool valid = (i < NANCH);
                unsigned int u = valid ? __float_as_uint(cl[i]) : 0u;
                int bin = (int)(u >> 24);
                unsigned long long act = __ballot(valid);
                while (act) {
                    int leader = (int)__ffsll((long long)act) - 1;
                    int lbin = __shfl(bin, leader);
                    unsigned long long sm = __ballot(valid && (bin == lbin));
                    if (lane == leader) atomicAdd(&sh.s.hist[hofs + lbin], (int)__popcll(sm));
                    act &= ~sm;
                }
            }
        } else {
            for (int i = tid; i < NANCH; i += 256) {
                unsigned int u = __float_as_uint(cl[i]);
                if ((u & maskHigh) == prefix)
                    atomicAdd(&sh.s.hist[hofs + ((u >> shift) & 0xFF)], 1);
            }
        }
        __syncthreads();
        int h = sh.s.hist[tid] + sh.s.hist[HSTRIDE + tid]
              + sh.s.hist[2 * HSTRIDE + tid] + sh.s.hist[3 * HSTRIDE + tid];
        int v = h;
#pragma unroll
        for (int off = 1; off < 64; off <<= 1) {
            int u2 = __shfl_up(v, off);
            if (lane >= off) v += u2;
        }
        if (lane == 63) sh.s.wsum[w] = v;
        __syncthreads();
        {
            int add = 0;
            for (int i = 0; i < w; ++i) add += sh.s.wsum[i];
            int incl = v + add, excl = incl - h;
            if (excl <= k && k < incl) {
                sh.s.prefix = prefix | ((unsigned int)tid << shift);
                sh.s.k = k - excl;
            }
        }
        __syncthreads();
        prefix = sh.s.prefix;
        k = sh.s.k;
        __syncthreads();
    }
    const unsigned int TT = prefix;

    // stable (index-order) resolution of the k-th equal element
    {
        const int CH = 35;
        int lo = tid * CH; if (lo > NANCH) lo = NANCH;
        int hi = lo + CH; if (hi > NANCH) hi = NANCH;
        int cnt = 0;
        for (int i = lo; i < hi; ++i)
            cnt += (__float_as_uint(cl[i]) == TT);
        int v2 = cnt;
#pragma unroll
        for (int off = 1; off < 64; off <<= 1) {
            int u2 = __shfl_up(v2, off);
            if (lane >= off) v2 += u2;
        }
        if (lane == 63) sh.s.wsum[w] = v2;
        __syncthreads();
        int add = 0;
        for (int i = 0; i < w; ++i) add += sh.s.wsum[i];
        int incl = v2 + add, excl = incl - cnt;
        if (excl <= k && k < incl) {
            int need = k - excl, idx = NANCH - 1;
            for (int i = lo; i < hi; ++i) {
                if (__float_as_uint(cl[i]) == TT) {
                    if (need == 0) { idx = i; break; }
                    --need;
                }
            }
            sh.s.thr = idx;
        }
    }
    __syncthreads();

    const float thr = (float)sh.s.thr;   // quirk: threshold is the argsort INDEX
    float local = 0.f;
    for (int i = tid; i < NANCH; i += 256) {
        float c = cl[i];
        if (c > thr) local += c;
    }
    for (int off = 32; off; off >>= 1) local += __shfl_xor(local, off);
    if (lane == 0) sh.s.fred[w] = local;
    __syncthreads();
    if (tid == 0) {
        float t = ALD_F(&row_pos[b]);
        out[b] = t + sh.s.fred[0] + sh.s.fred[1] + sh.s.fred[2] + sh.s.fred[3];
    }
}

extern "C" void kernel_launch(void* const* d_in, const int* in_sizes, int n_in,
                              void* d_out, int out_size, void* d_ws, size_t ws_size,
                              hipStream_t stream) {
    const float* pred_conf = (const float*)d_in[0];
    const float* pred_loc  = (const float*)d_in[1];
    const float* gt_conf   = (const float*)d_in[2];
    const float* gt_loc    = (const float*)d_in[3];
    float* out = (float*)d_out;

    int*   pos_buckets = (int*)d_ws;                     // [0, 4096)
    float* row_pos     = (float*)((char*)d_ws + 4096);   // [4096, 4608)
    int*   done        = (int*)((char*)d_ws + 4608);     // [4608, 4612)
    float* locp        = (float*)((char*)d_ws + 5120);   // [5120, 14080): 2240 floats
    float* vals        = (float*)((char*)d_ws + 16384);  // [64*8732] floats

    hipMemsetAsync(d_ws, 0, 8192, stream);               // buckets + row_pos + done

    fused_kernel<<<NLOC_BLK + NCONF_BLK + NSEL_BLK, 256, 0, stream>>>(
        pred_conf, gt_conf, pred_loc, gt_loc, vals, pos_buckets, row_pos,
        locp, done, out);
}

// Round 8
// 386.009 us; speedup vs baseline: 1.9488x; 1.9488x over previous
//
#include <hip/hip_runtime.h>
#include <math.h>

#define NCLS 81
#define NANCH 8732
#define NB 64
#define BUCKET_STRIDE 16     // 64 B cacheline spread for int buckets
#define HSTRIDE 257          // bank-decorrelated histogram copy stride (ints)
#define NLOC_BLK 2240        // 35 chunks * 64 batch rows (leading blocks)
#define TILE_F 5184          // 64 anchors * 81 classes floats
#define TILE_F4 1296         // float4 count per tile

// ---------------- Kernel A: loc partials + R0 block-coop conf ----------------
// Blocks [0,NLOC): loc smooth-L1 partial per block -> locp (no atomics).
// Blocks [NLOC, NLOC+8732): conf. Block-cooperative global_load_lds staging of a
// 64-anchor tile (21 KB), gt one-hot scan to labels, ONE barrier (drains DMA +
// LDS writes), then 4-lane/anchor softmax. The 8732-block turnover is the
// pipeline: freshly-dispatched blocks issue DMA while resident blocks compute.
// Measured best conf structure (125 us, ~92% of the ~3.1 TB/s read ceiling).
__global__ __launch_bounds__(256) void conf_loc_kernel(
    const float* __restrict__ pred_conf,
    const float* __restrict__ gt_conf,
    const float* __restrict__ pred_loc,
    const float* __restrict__ gt_loc,
    float* __restrict__ cl_out,       // [B*N] cl_neg (0 for positives)
    int* __restrict__ pos_buckets,    // [64*BUCKET_STRIDE], pre-zeroed
    float* __restrict__ row_pos,      // [128] per-row positive-loss sums, pre-zeroed
    float* __restrict__ locp)         // [2240] loc per-block partials (pure writes)
{
    __shared__ float sx[TILE_F];      // 20736 B pred tile
    __shared__ int label_s[64];
    __shared__ int pcnt[4];
    __shared__ float red[4];

    const int tid = threadIdx.x;
    const int lane = tid & 63, wid = tid >> 6;

    if (blockIdx.x < NLOC_BLK) {
        // ---- loc: smooth-L1-quirk loss; one partial per block ----
        const int bid = blockIdx.x;
        const int b = bid & 63;
        const int chunk = bid >> 6;     // 0..34
        const int idx = chunk * 256 + tid;
        float local = 0.f;
        if (idx < NANCH) {
            const float4* p = (const float4*)(pred_loc + (size_t)b * (NANCH * 4));
            const float4* g = (const float4*)(gt_loc + (size_t)b * (NANCH * 4));
            float4 pv = p[idx];
            float4 gv = g[idx];
            float a0 = fabsf(pv.x - gv.x), a1 = fabsf(pv.y - gv.y);
            float a2 = fabsf(pv.z - gv.z), a3 = fabsf(pv.w - gv.w);
            local  = (a0 > 1.f) ? (a0 - 0.5f) : 0.f;
            local += (a1 > 1.f) ? (a1 - 0.5f) : 0.f;
            local += (a2 > 1.f) ? (a2 - 0.5f) : 0.f;
            local += (a3 > 1.f) ? (a3 - 0.5f) : 0.f;
        }
        for (int off = 32; off; off >>= 1) local += __shfl_xor(local, off);
        if (lane == 0) red[wid] = local;
        __syncthreads();
        if (tid == 0) locp[bid] = red[0] + red[1] + red[2] + red[3];
        return;
    }

    // ---- conf ----
    const int cb = blockIdx.x - NLOC_BLK;       // 0..8731
    const size_t tbase = (size_t)cb * TILE_F;
    const float4* p4 = (const float4*)(pred_conf + tbase);
    const float4* g4 = (const float4*)(gt_conf + tbase);

    // async stage pred tile: chunk c = 64 lanes * 16 B contiguous
    for (int c = wid; c < 21; c += 4) {
        int f4 = c * 64 + lane;
        if (f4 < TILE_F4) {
            __builtin_amdgcn_global_load_lds(
                (const __attribute__((address_space(1))) unsigned int*)(p4 + f4),
                (__attribute__((address_space(3))) unsigned int*)(&sx[f4 * 4]),
                16, 0, 0);
        }
    }

    // gt scan: coalesced float4; each anchor row has exactly one nonzero
    int mycnt = 0;
#pragma unroll
    for (int i = 0; i < 6; ++i) {
        int k = tid + 256 * i;
        if (k < TILE_F4) {
            float4 g = g4[k];
            int base = 4 * k;
            float gv[4] = {g.x, g.y, g.z, g.w};
#pragma unroll
            for (int t = 0; t < 4; ++t) {
                if (gv[t] != 0.0f) {
                    int gidx = base + t;
                    int a = gidx / NCLS;
                    int cls = gidx - a * NCLS;
                    label_s[a] = cls;
                    mycnt += (cls != 0);
                }
            }
        }
    }
    for (int off = 32; off; off >>= 1) mycnt += __shfl_xor(mycnt, off);
    if (lane == 0) pcnt[wid] = mycnt;

    __syncthreads();   // drains global_load_lds + label writes

    const int a = tid >> 2;
    const int q = tid & 3;
    const float* xr = sx + a * NCLS;

    float s0 = 0.f, s1 = 0.f, s2 = 0.f;
#pragma unroll
    for (int j = 0; j < 21; ++j) {
        int c = q + 4 * j;
        if (c < NCLS) {
            float e = __expf(xr[c]);
            if (j % 3 == 0) s0 += e; else if (j % 3 == 1) s1 += e; else s2 += e;
        }
    }
    float s = s0 + s1 + s2;
    s += __shfl_xor(s, 1);
    s += __shfl_xor(s, 2);
    const float lse = __logf(s);

    const int anchor = cb * 64 + a;
    float conf_loss = 0.f;
    bool posf = false;
    if (q == 0) {
        int lbl = label_s[a];
        conf_loss = lse - xr[lbl];              // one-hot dot == x[label] bit-exact
        posf = (lbl != 0);
        cl_out[anchor] = posf ? 0.0f : conf_loss;
    }

    const int b = anchor / NANCH;
    const float contrib = posf ? conf_loss : 0.0f;
    const int bF = __builtin_amdgcn_readfirstlane(b);
    float c0 = (b == bF) ? contrib : 0.0f;
    float c1 = contrib - c0;                    // row-boundary spillover
    for (int off = 32; off; off >>= 1) {
        c0 += __shfl_xor(c0, off);
        c1 += __shfl_xor(c1, off);
    }
    if (lane == 0) {
        if (c0 != 0.f) atomicAdd(&row_pos[bF], c0);
        if (c1 != 0.f) atomicAdd(&row_pos[bF + 1], c1);
    }
    if (tid == 0) {
        int tot = pcnt[0] + pcnt[1] + pcnt[2] + pcnt[3];
        if (tot) atomicAdd(&pos_buckets[(cb & 63) * BUCKET_STRIDE], tot);
    }
}

// ---------------- Kernel B: hard-negative mining + conf total + loc total ----------------
// grid = 64 rows, block = 1024. Radix-256 select over float bits, 4 rounds.
// Round 0: ballot match-any (values cluster into 1-3 exponent bins -> ~3 loop
// iters, one atomic per distinct bin per wave). Rounds 1-3: plain atomics,
// 4 copies at stride 257 (bank-decorrelated). Wave 1 sums loc partials.
__global__ __launch_bounds__(1024) void select_kernel(
    const float* __restrict__ val,
    const int* __restrict__ pos_buckets,
    const float* __restrict__ row_pos,
    const float* __restrict__ locp,
    float* __restrict__ out)
{
    __shared__ float cl[NANCH];
    __shared__ int hist[4 * HSTRIDE];
    __shared__ int wsum[16];
    __shared__ float fred[16];
    __shared__ int sh_numpos;
    __shared__ unsigned int sh_prefix;
    __shared__ int sh_k, sh_thr;

    const int b = blockIdx.x;
    const int tid = threadIdx.x;
    const int lane = tid & 63, w = tid >> 6;
    const int hofs = (w & 3) * HSTRIDE;
    const float* row = val + b * NANCH;

    if (tid < 64) {
        int v = pos_buckets[tid * BUCKET_STRIDE];
        for (int off = 32; off; off >>= 1) v += __shfl_xor(v, off);
        if (tid == 0) sh_numpos = v;
    } else if (tid < 128) {
        // loc total: sum 35 chunk partials for row b (wave 1, independent)
        float v = (lane < 35) ? locp[lane * 64 + b] : 0.f;
        for (int off = 32; off; off >>= 1) v += __shfl_xor(v, off);
        if (lane == 0) out[64 + b] = v;
    }
    for (int i = tid; i < NANCH; i += 1024) cl[i] = row[i];
    __syncthreads();

    int k = 3 * sh_numpos;               // ref: int(3.0 * num_pos), global scalar
    if (k > NANCH - 1) k = NANCH - 1;
    if (k < 0) k = 0;

    unsigned int prefix = 0u;
    for (int r = 0; r < 4; ++r) {
        const int shift = 24 - 8 * r;
        const unsigned int maskHigh = (r == 0) ? 0u : (0xFFFFFFFFu << (shift + 8));
        for (int j = tid; j < 4 * HSTRIDE; j += 1024) hist[j] = 0;
        __syncthreads();
        if (r == 0) {
            // wave-aggregated histogram of the exponent byte
            for (int i0 = 0; i0 < 9216; i0 += 1024) {
                int i = i0 + tid;
                bool valid = (i < NANCH);
                unsigned int u = valid ? __float_as_uint(cl[i]) : 0u;
                int bin = (int)(u >> 24);
                unsigned long long act = __ballot(valid);
                while (act) {
                    int leader = (int)__ffsll((long long)act) - 1;
                    int lbin = __shfl(bin, leader);
                    unsigned long long sm = __ballot(valid && (bin == lbin));
                    if (lane == leader) atomicAdd(&hist[hofs + lbin], (int)__popcll(sm));
                    act &= ~sm;
                }
            }
        } else {
            for (int i = tid; i < NANCH; i += 1024) {
                unsigned int u = __float_as_uint(cl[i]);
                if ((u & maskHigh) == prefix)
                    atomicAdd(&hist[hofs + ((u >> shift) & 0xFF)], 1);
            }
        }
        __syncthreads();
        int h = 0, v = 0;
        if (tid < 256) {
            h = hist[tid] + hist[HSTRIDE + tid] + hist[2 * HSTRIDE + tid]
              + hist[3 * HSTRIDE + tid];
            v = h;
#pragma unroll
            for (int off = 1; off < 64; off <<= 1) {
                int u2 = __shfl_up(v, off);
                if (lane >= off) v += u2;
            }
            if (lane == 63) wsum[w] = v;
        }
        __syncthreads();
        if (tid < 256) {
            int add = 0;
            for (int i = 0; i < w; ++i) add += wsum[i];
            int incl = v + add, excl = incl - h;
            if (excl <= k && k < incl) {
                sh_prefix = prefix | ((unsigned int)tid << shift);
                sh_k = k - excl;
            }
        }
        __syncthreads();
        prefix = sh_prefix;
        k = sh_k;
        __syncthreads();
    }
    const unsigned int T = prefix;

    // stable (index-order) resolution of the k-th equal element
    const int CHUNK = 9;
    int lo = tid * CHUNK; if (lo > NANCH) lo = NANCH;
    int hi = lo + CHUNK; if (hi > NANCH) hi = NANCH;
    int cnt = 0;
    for (int i = lo; i < hi; ++i)
        cnt += (__float_as_uint(cl[i]) == T);
    int v2 = cnt;
#pragma unroll
    for (int off = 1; off < 64; off <<= 1) {
        int u2 = __shfl_up(v2, off);
        if (lane >= off) v2 += u2;
    }
    if (lane == 63) wsum[w] = v2;
    __syncthreads();
    if (tid < 16) {
        int s = wsum[tid];
#pragma unroll
        for (int off = 1; off < 16; off <<= 1) {
            int u2 = __shfl_up(s, off);
            if (lane >= off) s += u2;
        }
        wsum[tid] = s;
    }
    __syncthreads();
    {
        int add = (w == 0) ? 0 : wsum[w - 1];
        int incl = v2 + add, excl = incl - cnt;
        if (excl <= k && k < incl) {
            int need = k - excl, idx = NANCH - 1;
            for (int i = lo; i < hi; ++i) {
                if (__float_as_uint(cl[i]) == T) {
                    if (need == 0) { idx = i; break; }
                    --need;
                }
            }
            sh_thr = idx;
        }
    }
    __syncthreads();

    const float thr = (float)sh_thr;     // quirk: threshold is the argsort INDEX
    float local = 0.f;
    for (int i = tid; i < NANCH; i += 1024) {
        float c = cl[i];
        if (c > thr) local += c;
    }
    for (int off = 32; off; off >>= 1) local += __shfl_xor(local, off);
    if (lane == 0) fred[w] = local;
    __syncthreads();
    if (tid == 0) {
        float t = row_pos[b];
        for (int i = 0; i < 16; ++i) t += fred[i];
        out[b] = t;
    }
}

extern "C" void kernel_launch(void* const* d_in, const int* in_sizes, int n_in,
                              void* d_out, int out_size, void* d_ws, size_t ws_size,
                              hipStream_t stream) {
    const float* pred_conf = (const float*)d_in[0];
    const float* pred_loc  = (const float*)d_in[1];
    const float* gt_conf   = (const float*)d_in[2];
    const float* gt_loc    = (const float*)d_in[3];
    float* out = (float*)d_out;

    int*   pos_buckets = (int*)d_ws;                     // [0, 4096)
    float* row_pos     = (float*)((char*)d_ws + 4096);   // [4096, 4608)
    float* locp        = (float*)((char*)d_ws + 5120);   // [5120, 14080): 2240 floats
    float* vals        = (float*)((char*)d_ws + 16384);  // [64*8732] floats

    hipMemsetAsync(d_ws, 0, 8192, stream);               // pos_buckets + row_pos

    conf_loc_kernel<<<NLOC_BLK + NANCH, 256, 0, stream>>>(
        pred_conf, gt_conf, pred_loc, gt_loc, vals, pos_buckets, row_pos, locp);
    select_kernel<<<NB, 1024, 0, stream>>>(vals, pos_buckets, row_pos, locp, out);
}